// Round 1
// 1196.594 us; speedup vs baseline: 1.8468x; 1.8468x over previous
//
#include <hip/hip_runtime.h>

// Correlation layer (FlowNet-style), stride=1, 7x7 window.
// B=8, C=128, H=192, W=448. out[b][k][y][x], k=(dj+3)*7+(di+3),
// out = mean_c first[b,c,y,x]*second[b,c,y+dj,x+di] (zero-padded).
//
// v2: dj-split across two block types to keep accumulators in VGPRs.
//   type0 (blocks 0..671):    dj in {-3..0} -> 28 outputs/pixel, acc = 112 VGPRs
//   type1 (blocks 672..1343): dj in { 1..3} -> 21 outputs/pixel, acc =  84 VGPRs
// Previous version held 49 float4 accs (196 regs) -> compiler capped at 128 VGPRs
// and spilled (WRITE_SIZE 1.66 GB vs 135 MB output). Split kills the spills,
// doubles the grid (672 -> 1344) and lets __launch_bounds__(256,3) hold
// 3 blocks/CU (12 waves/CU) for latency hiding.

constexpr int Bn = 8, Cn = 128, Hn = 192, Wn = 448;
constexpr int TY  = 16;          // y rows per tile
constexpr int TXQ = 16;          // threads along x
constexpr int TXP = 64;          // x pixels per tile (4 per thread)
constexpr int RW  = TXP + 8;     // 72 floats per staged row (halo 4 each side)
constexpr int NQ  = RW / 4;      // 18 float4 quads per row
constexpr int HRMAX = TY + 3;    // 19 staged rows max (type0)
constexpr int XT = Wn / TXP;     // 7
constexpr int YT = Hn / TY;      // 12
constexpr int NTILE = XT * YT * Bn; // 672 tiles; grid = 2*NTILE
constexpr int PLANE = Hn * Wn;   // 86016

template<int HALF>
__device__ __forceinline__ void corr_body(
    const float* __restrict__ first,
    const float* __restrict__ second,
    float* __restrict__ out,
    float (*smem)[HRMAX][RW],    // [2][19][72] double-buffered
    int id, int tid)
{
    constexpr int NDJ    = HALF ? 3 : 4;          // dj rows this half computes
    constexpr int RBASE  = HALF ? 1 : -3;         // global row of staged row 0
    constexpr int KBASE  = HALF ? 28 : 0;         // output plane offset
    constexpr int HR2    = HALF ? (TY + 2) : (TY + 3);  // 18 / 19 staged rows
    constexpr int NTASK2 = HR2 * NQ;              // 324 / 342 staging quads
    constexpr int NACC   = NDJ * 7;               // 21 / 28 float4 accumulators

    const int tx = tid & (TXQ - 1);
    const int ty = tid >> 4;

    const int by = id / (XT * Bn);
    const int rr = id - by * (XT * Bn);
    const int bx = rr % XT;
    const int bz = rr / XT;

    const int x0 = bx * TXP;
    const int y0 = by * TY;

    const float* fplane0 = first  + (size_t)bz * Cn * PLANE;
    const float* splane0 = second + (size_t)bz * Cn * PLANE;

    // ---- staging task setup (fixed per thread across all channels) ----
    const int t1 = tid + 256;
    const bool has1 = (t1 < NTASK2);
    const int r0 = tid / NQ, q0 = tid - r0 * NQ;
    const int r1 = t1  / NQ, q1 = t1  - r1 * NQ;

    const int gy0 = y0 + RBASE + r0, gx0 = x0 - 4 + 4 * q0;
    const int gy1 = y0 + RBASE + r1, gx1 = x0 - 4 + 4 * q1;

    bool ok0[4], ok1[4];
    const bool row0ok = (gy0 >= 0) && (gy0 < Hn);
    const bool row1ok = (gy1 >= 0) && (gy1 < Hn);
#pragma unroll
    for (int j = 0; j < 4; ++j) {
        ok0[j] = row0ok && (gx0 + j >= 0) && (gx0 + j < Wn);
        ok1[j] = row1ok && (gx1 + j >= 0) && (gx1 + j < Wn);
    }
    // clamped (always-valid) addresses; OOB elems zeroed via masks
    const int soff0 = min(max(gy0, 0), Hn - 1) * Wn + min(max(gx0, 0), Wn - 4);
    const int soff1 = min(max(gy1, 0), Hn - 1) * Wn + min(max(gx1, 0), Wn - 4);

    const int foff = (y0 + ty) * Wn + x0 + 4 * tx; // this thread's 4 pixels

    auto loadmask = [](const float* p, int off, const bool* ok) {
        float4 v = *reinterpret_cast<const float4*>(p + off);
        v.x = ok[0] ? v.x : 0.0f;
        v.y = ok[1] ? v.y : 0.0f;
        v.z = ok[2] ? v.z : 0.0f;
        v.w = ok[3] ? v.w : 0.0f;
        return v;
    };

    float4 acc[NACC];
#pragma unroll
    for (int k = 0; k < NACC; ++k) acc[k] = make_float4(0.f, 0.f, 0.f, 0.f);

    // ---- prologue: stage channel 0 into buf 0, load first(c=0) ----
    {
        float4 v0 = loadmask(splane0, soff0, ok0);
        *reinterpret_cast<float4*>(&smem[0][r0][4 * q0]) = v0;
        if (has1) {
            float4 v1 = loadmask(splane0, soff1, ok1);
            *reinterpret_cast<float4*>(&smem[0][r1][4 * q1]) = v1;
        }
    }
    float4 fcur = *reinterpret_cast<const float4*>(fplane0 + foff);
    __syncthreads();

    int buf = 0;
    for (int c = 0; c < Cn; ++c) {
        const bool pf = (c + 1 < Cn);
        float4 p0, p1, fnext;
        if (pf) { // issue next channel's loads early (hidden under compute)
            const float* sp = splane0 + (size_t)(c + 1) * PLANE;
            p0 = loadmask(sp, soff0, ok0);
            if (has1) p1 = loadmask(sp, soff1, ok1);
            fnext = *reinterpret_cast<const float4*>(fplane0 + (size_t)(c + 1) * PLANE + foff);
        }

        const float(*sb)[RW] = smem[buf];
#pragma unroll
        for (int djl = 0; djl < NDJ; ++djl) {
            // staged row (ty+djl) holds global row y0+ty+dj for this half
            const float* rp = &sb[ty + djl][4 * tx];
            float4 w0 = *reinterpret_cast<const float4*>(rp);
            float4 w1 = *reinterpret_cast<const float4*>(rp + 4);
            float4 w2 = *reinterpret_cast<const float4*>(rp + 8);
            float w[12] = {w0.x, w0.y, w0.z, w0.w,
                           w1.x, w1.y, w1.z, w1.w,
                           w2.x, w2.y, w2.z, w2.w};
#pragma unroll
            for (int di = 0; di < 7; ++di) {
                float4& a = acc[djl * 7 + di];
                a.x = fmaf(fcur.x, w[1 + di], a.x);
                a.y = fmaf(fcur.y, w[2 + di], a.y);
                a.z = fmaf(fcur.z, w[3 + di], a.z);
                a.w = fmaf(fcur.w, w[4 + di], a.w);
            }
        }

        if (pf) {
            float(*sn)[RW] = smem[buf ^ 1];
            *reinterpret_cast<float4*>(&sn[r0][4 * q0]) = p0;
            if (has1) *reinterpret_cast<float4*>(&sn[r1][4 * q1]) = p1;
            fcur = fnext;
        }
        __syncthreads(); // writes to buf^1 done; reads of buf done
        buf ^= 1;
    }

    // ---- epilogue: mean (/128) and store ----
    const float scale = 1.0f / 128.0f;
    float* op = out + ((size_t)bz * 49 + KBASE) * PLANE + foff;
#pragma unroll
    for (int k = 0; k < NACC; ++k) {
        float4 a = acc[k];
        a.x *= scale; a.y *= scale; a.z *= scale; a.w *= scale;
        *reinterpret_cast<float4*>(op + (size_t)k * PLANE) = a;
    }
}

__global__ __launch_bounds__(256, 3)
void corr_k(const float* __restrict__ first,
            const float* __restrict__ second,
            float* __restrict__ out)
{
    __shared__ __align__(16) float smem[2][HRMAX][RW]; // 10.9 KB double-buffered

    // type pairs are NTILE=672 apart; 672 % 8 == 0 -> same XCD heuristic,
    // so both halves of a tile share first/second reads in that XCD's L2.
    const int id = blockIdx.x;
    if (id < NTILE) corr_body<0>(first, second, out, smem, id,          threadIdx.x);
    else            corr_body<1>(first, second, out, smem, id - NTILE,  threadIdx.x);
}

extern "C" void kernel_launch(void* const* d_in, const int* in_sizes, int n_in,
                              void* d_out, int out_size, void* d_ws, size_t ws_size,
                              hipStream_t stream) {
    const float* first  = (const float*)d_in[0];
    const float* second = (const float*)d_in[1];
    // d_in[2] = intStride (always 1 for this problem)
    float* out = (float*)d_out;
    corr_k<<<NTILE * 2, 256, 0, stream>>>(first, second, out);
}